// Round 4
// baseline (286.030 us; speedup 1.0000x reference)
//
#include <hip/hip_runtime.h>

// Problem constants
#define Bn 2
#define Tdim 2048
#define Ddim 1024
#define Hn 16
#define HD 64

typedef unsigned short u16;
typedef unsigned int u32;
typedef __attribute__((ext_vector_type(8))) __bf16 bf16x8;
typedef __attribute__((ext_vector_type(4))) float f32x4;

struct alignas(8) U16x4 { u16 x, y, z, w; };

__device__ __forceinline__ u16 f2bf(float f) {
  union { float f; u32 i; } v; v.f = f;
  u32 x = v.i;
  u32 r = (x + 0x7fffu + ((x >> 16) & 1u)) >> 16;
  return (u16)r;
}

__device__ __forceinline__ f32x4 mfma16(bf16x8 a, bf16x8 b, f32x4 c) {
  return __builtin_amdgcn_mfma_f32_16x16x32_bf16(a, b, c, 0, 0, 0);
}

// ---------------- weight transpose + f32->bf16 convert (1024x1024) ----------------
__global__ __launch_bounds__(256) void transpose_k(const float* __restrict__ src,
                                                   u16* __restrict__ dst) {
  __shared__ u16 tile[32][33];
  const int tx = threadIdx.x, ty = threadIdx.y;
  const int x = blockIdx.x * 32 + tx;
  const int y0 = blockIdx.y * 32;
#pragma unroll
  for (int j = 0; j < 32; j += 8) tile[ty + j][tx] = f2bf(src[(size_t)(y0 + ty + j) * Ddim + x]);
  __syncthreads();
  const int xo = blockIdx.y * 32 + tx;
  const int yo0 = blockIdx.x * 32;
#pragma unroll
  for (int j = 0; j < 32; j += 8) dst[(size_t)(yo0 + ty + j) * Ddim + xo] = tile[tx][ty + j];
}

// ---------------- fused QKV projection GEMM ----------------
// C(4096x1024) = X(4096x1024 f32) * W (via pre-transposed bf16 Wt)
// z=0 -> Q (B,H,T,64) bf16; z=1 -> K bf16; z=2 -> V stored transposed (B,H,64,T) bf16
__global__ __launch_bounds__(256, 2) void gemm_qkv(
    const float* __restrict__ X,
    const u16* __restrict__ WqT, const u16* __restrict__ WkT, const u16* __restrict__ WvT,
    const float* __restrict__ bq, const float* __restrict__ bk, const float* __restrict__ bv,
    u16* __restrict__ Q, u16* __restrict__ K, u16* __restrict__ Vt) {
  const int z = blockIdx.z;
  const u16* Wt = (z == 0) ? WqT : (z == 1) ? WkT : WvT;
  const float* bias = (z == 0) ? bq : (z == 1) ? bk : bv;
  u16* QK = (z == 0) ? Q : K;

  __shared__ alignas(16) u16 Alds[128 * 32];
  __shared__ alignas(16) u16 Blds[128 * 32];
  const int tid = threadIdx.x;
  const int w = tid >> 6, lane = tid & 63, ln = lane & 15, quad = lane >> 4;
  const int wm = (w >> 1) * 64, wn = (w & 1) * 64;
  const int tm = blockIdx.x * 128, tn = blockIdx.y * 128;

  f32x4 acc[4][4] = {};

  for (int k0 = 0; k0 < Ddim; k0 += 32) {
    __syncthreads();
    // staging: flat element e = rho*2048 + tid*8; row=e>>5, col=e&31
#pragma unroll
    for (int rho = 0; rho < 2; rho++) {
      const int e = rho * 2048 + tid * 8;
      const int row = e >> 5, col = e & 31;
      const float* xp = &X[(size_t)(tm + row) * Ddim + k0 + col];
      u16 tmp[8];
#pragma unroll
      for (int j = 0; j < 8; j++) tmp[j] = f2bf(xp[j]);
      *(bf16x8*)&Alds[e] = *(const bf16x8*)tmp;
      *(bf16x8*)&Blds[e] = *(const bf16x8*)&Wt[(size_t)(tn + row) * Ddim + k0 + col];
    }
    __syncthreads();
    bf16x8 af[4], bfr[4];
#pragma unroll
    for (int i = 0; i < 4; i++)
      af[i] = *(const bf16x8*)&Alds[(wm + i * 16 + ln) * 32 + quad * 8];
#pragma unroll
    for (int i = 0; i < 4; i++)
      bfr[i] = *(const bf16x8*)&Blds[(wn + i * 16 + ln) * 32 + quad * 8];
#pragma unroll
    for (int mi = 0; mi < 4; mi++)
#pragma unroll
      for (int ni = 0; ni < 4; ni++)
        acc[mi][ni] = mfma16(af[mi], bfr[ni], acc[mi][ni]);
  }

#pragma unroll
  for (int mi = 0; mi < 4; mi++) {
#pragma unroll
    for (int ni = 0; ni < 4; ni++) {
      const int gm0 = tm + wm + mi * 16 + quad * 4;  // 4 consecutive rows (reg axis)
      const int gn = tn + wn + ni * 16 + ln;
      const float bv_ = bias[gn];
      const int hh = gn >> 6, dd = gn & 63;
      const int b0 = gm0 >> 11, t0 = gm0 & 2047;
      if (z < 2) {
        u16* p = QK + (((size_t)(b0 * Hn + hh) * Tdim) + t0) * HD + dd;
#pragma unroll
        for (int r = 0; r < 4; r++) p[r * HD] = f2bf(acc[mi][ni][r] + bv_);
      } else {
        U16x4 pk;
        pk.x = f2bf(acc[mi][ni][0] + bv_);
        pk.y = f2bf(acc[mi][ni][1] + bv_);
        pk.z = f2bf(acc[mi][ni][2] + bv_);
        pk.w = f2bf(acc[mi][ni][3] + bv_);
        *(U16x4*)&Vt[((size_t)(b0 * Hn + hh) * HD + dd) * Tdim + t0] = pk;
      }
    }
  }
}

// ---------------- flash attention (causal + ALiBi), bf16 in / bf16 out ----------------
// grid: (T/128, B*H); block 256 (4 waves). Each wave owns 32 q-rows.
__global__ __launch_bounds__(256, 2) void attn_k(
    const u16* __restrict__ Q, const u16* __restrict__ K, const u16* __restrict__ Vt,
    u16* __restrict__ O) {
  __shared__ alignas(16) u16 Klds[128 * 64];   // 16KB  (key rows x hd)
  __shared__ alignas(16) u16 Vtlds[64 * 128];  // 16KB  (hd x key)
  __shared__ alignas(16) u16 Pq[16384];        // 32KB: Q staging, then per-wave P (32x128)

  const int qt = blockIdx.x, bh = blockIdx.y;
  const int b = bh >> 4, h = bh & 15;
  const int q0 = qt * 128;
  const int tid = threadIdx.x;
  const int w = tid >> 6, lane = tid & 63, ln = lane & 15, quad = lane >> 4;

  const u16* Qh = Q + (size_t)bh * Tdim * HD;
  const u16* Kh = K + (size_t)bh * Tdim * HD;
  const u16* Vh = Vt + (size_t)bh * HD * Tdim;
  const float slope = exp2f(-0.5f * (float)(h + 1));

  // stage Q tile (128x64) into Pq[0..8192): flat e, row=e>>6, col=e&63
#pragma unroll
  for (int c = 0; c < 4; c++) {
    const int e = c * 2048 + tid * 8;
    const int row = e >> 6, col = e & 63;
    bf16x8 v = *(const bf16x8*)&Qh[(size_t)(q0 + row) * HD + col];
    *(bf16x8*)&Pq[e] = v;
  }
  __syncthreads();

  bf16x8 qf[2][2];
#pragma unroll
  for (int mi = 0; mi < 2; mi++)
#pragma unroll
    for (int ks = 0; ks < 2; ks++)
      qf[mi][ks] = *(const bf16x8*)&Pq[(w * 32 + mi * 16 + ln) * 64 + ks * 32 + quad * 8];

  float mst[2][4], lst[2][4];
#pragma unroll
  for (int i = 0; i < 2; i++)
#pragma unroll
    for (int r = 0; r < 4; r++) { mst[i][r] = -INFINITY; lst[i][r] = 0.f; }
  f32x4 oacc[2][4] = {};

  u16* Pw = &Pq[w * 4096];  // this wave's P region: 32 x 128
  const int nkt = qt + 1;

  for (int kt = 0; kt < nkt; kt++) {
    const int kb = kt * 128;
    __syncthreads();  // protect previous iteration's LDS reads
#pragma unroll
    for (int c = 0; c < 4; c++) {
      const int e = c * 2048 + tid * 8;
      const int row = e >> 6, col = e & 63;      // K tile: 128 keys x 64
      bf16x8 vk = *(const bf16x8*)&Kh[(size_t)(kb + row) * HD + col];
      const int vr = e >> 7, vc = e & 127;       // V^T tile: 64 d x 128 keys
      bf16x8 vv = *(const bf16x8*)&Vh[(size_t)vr * Tdim + kb + vc];
      *(bf16x8*)&Klds[e] = vk;
      *(bf16x8*)&Vtlds[e] = vv;
    }
    __syncthreads();  // staging visible

    // S = Q K^T   (wave: 32q x 128k)
    f32x4 s[2][8] = {};
#pragma unroll
    for (int ks = 0; ks < 2; ks++) {
#pragma unroll
      for (int ni = 0; ni < 8; ni++) {
        bf16x8 kf = *(const bf16x8*)&Klds[(ni * 16 + ln) * 64 + ks * 32 + quad * 8];
        s[0][ni] = mfma16(qf[0][ks], kf, s[0][ni]);
        s[1][ni] = mfma16(qf[1][ks], kf, s[1][ni]);
      }
    }

    // scale + ALiBi + causal mask, row max
    float rmax[2][4];
#pragma unroll
    for (int i = 0; i < 2; i++)
#pragma unroll
      for (int r = 0; r < 4; r++) rmax[i][r] = -INFINITY;
    const bool diag = (kt == qt);
#pragma unroll
    for (int mi = 0; mi < 2; mi++) {
#pragma unroll
      for (int ni = 0; ni < 8; ni++) {
        const int n = kb + ni * 16 + ln;
        const float ab = -slope * (float)(Tdim - 1 - n);
#pragma unroll
        for (int r = 0; r < 4; r++) {
          float sv = s[mi][ni][r] * 0.125f + ab;
          if (diag) {
            const int qg = q0 + w * 32 + mi * 16 + quad * 4 + r;
            if (n > qg) sv = -1e30f;
          }
          s[mi][ni][r] = sv;
          rmax[mi][r] = fmaxf(rmax[mi][r], sv);
        }
      }
    }
#pragma unroll
    for (int mi = 0; mi < 2; mi++)
#pragma unroll
      for (int r = 0; r < 4; r++) {
#pragma unroll
        for (int off = 8; off >= 1; off >>= 1)
          rmax[mi][r] = fmaxf(rmax[mi][r], __shfl_xor(rmax[mi][r], off));
      }

    float alpha[2][4];
#pragma unroll
    for (int mi = 0; mi < 2; mi++)
#pragma unroll
      for (int r = 0; r < 4; r++) {
        const float mn = fmaxf(mst[mi][r], rmax[mi][r]);
        alpha[mi][r] = __expf(mst[mi][r] - mn);
        mst[mi][r] = mn;
      }

    float rsum[2][4] = {};
#pragma unroll
    for (int mi = 0; mi < 2; mi++) {
#pragma unroll
      for (int ni = 0; ni < 8; ni++) {
#pragma unroll
        for (int r = 0; r < 4; r++) {
          const float p = __expf(s[mi][ni][r] - mst[mi][r]);
          rsum[mi][r] += p;
          Pw[(mi * 16 + quad * 4 + r) * 128 + ni * 16 + ln] = f2bf(p);
        }
      }
    }
#pragma unroll
    for (int mi = 0; mi < 2; mi++)
#pragma unroll
      for (int r = 0; r < 4; r++) {
#pragma unroll
        for (int off = 8; off >= 1; off >>= 1)
          rsum[mi][r] += __shfl_xor(rsum[mi][r], off);
        lst[mi][r] = lst[mi][r] * alpha[mi][r] + rsum[mi][r];
      }
#pragma unroll
    for (int mi = 0; mi < 2; mi++)
#pragma unroll
      for (int nd = 0; nd < 4; nd++)
#pragma unroll
        for (int r = 0; r < 4; r++) oacc[mi][nd][r] *= alpha[mi][r];

    __syncthreads();  // P write -> read ordering

    // O += P * V   (P: A-layout from LDS; V: pre-transposed rows)
#pragma unroll
    for (int ks = 0; ks < 4; ks++) {
      bf16x8 pf0 = *(const bf16x8*)&Pw[(ln)*128 + ks * 32 + quad * 8];
      bf16x8 pf1 = *(const bf16x8*)&Pw[(16 + ln) * 128 + ks * 32 + quad * 8];
#pragma unroll
      for (int nd = 0; nd < 4; nd++) {
        bf16x8 vf = *(const bf16x8*)&Vtlds[(nd * 16 + ln) * 128 + ks * 32 + quad * 8];
        oacc[0][nd] = mfma16(pf0, vf, oacc[0][nd]);
        oacc[1][nd] = mfma16(pf1, vf, oacc[1][nd]);
      }
    }
  }

  // epilogue: write (b, t, h*64+d) bf16 intermediate
#pragma unroll
  for (int mi = 0; mi < 2; mi++) {
#pragma unroll
    for (int nd = 0; nd < 4; nd++) {
      const int d = nd * 16 + ln;
#pragma unroll
      for (int r = 0; r < 4; r++) {
        const int t = q0 + w * 32 + mi * 16 + quad * 4 + r;
        O[((size_t)(b * Tdim + t)) * Ddim + h * HD + d] =
            f2bf(oacc[mi][nd][r] / lst[mi][r]);
      }
    }
  }
}

// ---------------- output projection GEMM (bf16 x bf16 -> f32 out) ----------------
__global__ __launch_bounds__(256, 2) void gemm_out(
    const u16* __restrict__ A, const u16* __restrict__ WoT, const float* __restrict__ bo,
    float* __restrict__ C) {
  __shared__ alignas(16) u16 Alds[128 * 32];
  __shared__ alignas(16) u16 Blds[128 * 32];
  const int tid = threadIdx.x;
  const int w = tid >> 6, lane = tid & 63, ln = lane & 15, quad = lane >> 4;
  const int wm = (w >> 1) * 64, wn = (w & 1) * 64;
  const int tm = blockIdx.x * 128, tn = blockIdx.y * 128;

  f32x4 acc[4][4] = {};

  for (int k0 = 0; k0 < Ddim; k0 += 32) {
    __syncthreads();
#pragma unroll
    for (int rho = 0; rho < 2; rho++) {
      const int e = rho * 2048 + tid * 8;
      const int row = e >> 5, col = e & 31;
      bf16x8 va = *(const bf16x8*)&A[(size_t)(tm + row) * Ddim + k0 + col];
      bf16x8 vb = *(const bf16x8*)&WoT[(size_t)(tn + row) * Ddim + k0 + col];
      *(bf16x8*)&Alds[e] = va;
      *(bf16x8*)&Blds[e] = vb;
    }
    __syncthreads();
    bf16x8 af[4], bfr[4];
#pragma unroll
    for (int i = 0; i < 4; i++)
      af[i] = *(const bf16x8*)&Alds[(wm + i * 16 + ln) * 32 + quad * 8];
#pragma unroll
    for (int i = 0; i < 4; i++)
      bfr[i] = *(const bf16x8*)&Blds[(wn + i * 16 + ln) * 32 + quad * 8];
#pragma unroll
    for (int mi = 0; mi < 4; mi++)
#pragma unroll
      for (int ni = 0; ni < 4; ni++)
        acc[mi][ni] = mfma16(af[mi], bfr[ni], acc[mi][ni]);
  }

#pragma unroll
  for (int mi = 0; mi < 4; mi++) {
#pragma unroll
    for (int ni = 0; ni < 4; ni++) {
      const int gm0 = tm + wm + mi * 16 + quad * 4;
      const int gn = tn + wn + ni * 16 + ln;
      const float bv_ = bo[gn];
#pragma unroll
      for (int r = 0; r < 4; r++)
        C[(size_t)(gm0 + r) * Ddim + gn] = acc[mi][ni][r] + bv_;
    }
  }
}

extern "C" void kernel_launch(void* const* d_in, const int* in_sizes, int n_in,
                              void* d_out, int out_size, void* d_ws, size_t ws_size,
                              hipStream_t stream) {
  (void)in_sizes; (void)n_in; (void)out_size; (void)ws_size;
  const float* x  = (const float*)d_in[0];
  const float* Wq = (const float*)d_in[1];
  const float* bq = (const float*)d_in[2];
  const float* Wk = (const float*)d_in[3];
  const float* bk = (const float*)d_in[4];
  const float* Wv = (const float*)d_in[5];
  const float* bv = (const float*)d_in[6];
  const float* Wo = (const float*)d_in[7];
  const float* bo = (const float*)d_in[8];

  char* ws = (char*)d_ws;
  const size_t MB = 1024 * 1024;
  u16* WqT = (u16*)(ws + 0 * MB);   // 2MB bf16 1024x1024
  u16* WkT = (u16*)(ws + 2 * MB);
  u16* WvT = (u16*)(ws + 4 * MB);
  u16* WoT = (u16*)(ws + 6 * MB);
  u16* Qb  = (u16*)(ws + 8 * MB);   // 8MB bf16 (B,H,T,64)
  u16* Kb  = (u16*)(ws + 16 * MB);
  u16* Vtb = (u16*)(ws + 24 * MB);  // 8MB bf16 (B,H,64,T)
  u16* AO  = (u16*)(ws + 32 * MB);  // 8MB bf16 (B,T,D)

  dim3 tb(32, 8);
  transpose_k<<<dim3(32, 32), tb, 0, stream>>>(Wq, WqT);
  transpose_k<<<dim3(32, 32), tb, 0, stream>>>(Wk, WkT);
  transpose_k<<<dim3(32, 32), tb, 0, stream>>>(Wv, WvT);
  transpose_k<<<dim3(32, 32), tb, 0, stream>>>(Wo, WoT);

  gemm_qkv<<<dim3(32, 8, 3), 256, 0, stream>>>(x, WqT, WkT, WvT, bq, bk, bv, Qb, Kb, Vtb);
  attn_k<<<dim3(16, 32), 256, 0, stream>>>(Qb, Kb, Vtb, AO);
  gemm_out<<<dim3(32, 8), 256, 0, stream>>>(AO, WoT, bo, (float*)d_out);
}